// Round 2
// baseline (120.985 us; speedup 1.0000x reference)
//
#include <hip/hip_runtime.h>

// ROI bilinear pooling: img (1,200,200,512) fp32, rois (1,300,4) int32 [x,y,w,h]
// out (1,300,7,7,512) fp32.
// One WAVE (64 lanes) per (roi,py,px) position; each lane does 8 channels
// (2x float4) from each of the 4 source pixels -> 8 outstanding dwordx4
// loads per wave for latency hiding. 4 positions per 256-thread block.

#define IMG_W 200
#define NCH   512
#define NPOS  49   // 7*7

__global__ __launch_bounds__(256) void roi_bilinear_kernel(
    const float* __restrict__ img,
    const int*   __restrict__ rois,
    float*       __restrict__ out)
{
    int tid  = threadIdx.x;
    int wave = tid >> 6;          // 0..3: position within block
    int lane = tid & 63;          // 0..63: channel group

    int pos = blockIdx.x * 4 + wave;   // 0..14699, grid sized exactly
    int r   = pos / NPOS;
    int rem = pos - r * NPOS;
    int py  = rem / 7;
    int px  = rem - py * 7;

    int x0 = rois[4 * r + 0];
    int y0 = rois[4 * r + 1];
    int w  = rois[4 * r + 2];
    int h  = rois[4 * r + 3];

    // Strict IEEE fp32, op-for-op identical to the numpy/jax reference:
    // scale = h/7.0f; ys = y0 + py*scale  (no fma contraction)
    float sy = __fdiv_rn((float)h, 7.0f);
    float sx = __fdiv_rn((float)w, 7.0f);
    float ys = __fadd_rn((float)y0, __fmul_rn((float)py, sy));
    float xs = __fadd_rn((float)x0, __fmul_rn((float)px, sx));

    int ty = (int)floorf(ys);
    int tx = (int)floorf(xs);
    float fy = __fsub_rn(ys, (float)ty);
    float fx = __fsub_rn(xs, (float)tx);

    int by = min(ty + 1, y0 + h - 1);
    int bx = min(tx + 1, x0 + w - 1);

    const float4* p00 = (const float4*)(img + (size_t)(ty * IMG_W + tx) * NCH);
    const float4* p01 = (const float4*)(img + (size_t)(ty * IMG_W + bx) * NCH);
    const float4* p10 = (const float4*)(img + (size_t)(by * IMG_W + tx) * NCH);
    const float4* p11 = (const float4*)(img + (size_t)(by * IMG_W + bx) * NCH);
    float4*       po  = (float4*)(out + (size_t)pos * NCH);

    // Two float4 groups per lane: indices lane and lane+64 (both coalesced).
    int i0 = lane;
    int i1 = lane + 64;

    float4 a00 = p00[i0], b00 = p00[i1];
    float4 a01 = p01[i0], b01 = p01[i1];
    float4 a10 = p10[i0], b10 = p10[i1];
    float4 a11 = p11[i0], b11 = p11[i1];

    float gx = 1.0f - fx;
    float gy = 1.0f - fy;

    float4 oa, ob;
    oa.x = gy * (gx * a00.x + fx * a01.x) + fy * (gx * a10.x + fx * a11.x);
    oa.y = gy * (gx * a00.y + fx * a01.y) + fy * (gx * a10.y + fx * a11.y);
    oa.z = gy * (gx * a00.z + fx * a01.z) + fy * (gx * a10.z + fx * a11.z);
    oa.w = gy * (gx * a00.w + fx * a01.w) + fy * (gx * a10.w + fx * a11.w);
    ob.x = gy * (gx * b00.x + fx * b01.x) + fy * (gx * b10.x + fx * b11.x);
    ob.y = gy * (gx * b00.y + fx * b01.y) + fy * (gx * b10.y + fx * b11.y);
    ob.z = gy * (gx * b00.z + fx * b01.z) + fy * (gx * b10.z + fx * b11.z);
    ob.w = gy * (gx * b00.w + fx * b01.w) + fy * (gx * b10.w + fx * b11.w);

    po[i0] = oa;
    po[i1] = ob;
}

extern "C" void kernel_launch(void* const* d_in, const int* in_sizes, int n_in,
                              void* d_out, int out_size, void* d_ws, size_t ws_size,
                              hipStream_t stream)
{
    const float* img  = (const float*)d_in[0];   // 1*200*200*512 fp32
    const int*   rois = (const int*)d_in[1];     // 1*300*4 int32
    float*       out  = (float*)d_out;           // 1*300*7*7*512 fp32

    const int nroi = in_sizes[1] / 4;            // 300
    const int npos = nroi * NPOS;                // 14700
    dim3 grid(npos / 4);                         // 3675 blocks (14700 % 4 == 0)
    dim3 block(256);
    roi_bilinear_kernel<<<grid, block, 0, stream>>>(img, rois, out);
}